// Round 1
// baseline (377.249 us; speedup 1.0000x reference)
//
#include <hip/hip_runtime.h>
#include <math.h>

// VQ quantizer: z [N,64] fp32, codebook [512,64] fp32.
// out layout (all fp32): q_ste [N*64] | loss [1] | ids-as-float [N]
//
// R1-R4 history: LDS-bound 440 -> VMEM-bound 537 -> SMEM-latency 453 -> K-split 374us.
// R4's structure is fp32-VALU: absolute roofline 109us at 100% VALU; measured 47%
// VALUBusy because each K-iter drains lgkmcnt(0) on 256B scalar fetch (no SGPR
// room to double-buffer, SMEM returns OOO). MfmaUtil was 0%.
//
// R5: move the dot products to the matrix pipe. Split-bf16 (hh+hl+lh) MFMA
// computes s = z.c - 0.5*|c|^2 with ~1e-6 error; rows whose best-vs-runnerup
// margin exceeds STH=1e-3 (>>100x realistic worst error) are provably the fp32
// argmin. Ambiguous rows (~1-3%) are appended to a compacted list and re-solved
// by vq_fallback = verbatim R4 inner loop (verified absmax 0.0 semantics,
// identical tie rules). Correctness holds for ANY flag rate.
//
// mfma_f32_32x32x16_bf16, A=codebook(M=32 cw), B=z(N=32 rows):
//   C/D: col=lane&31 (z-row), row=(reg&3)+8*(reg>>2)+4*(lane>>5) (codeword)
//   -> per-lane 16 accs are 16 codewords of the lane's OWN row: argmin scan is
//      lane-local (med3/max/cndmask), one shfl_xor(32) pair-combine at the end.
// A/B frags: lane holds contiguous k = 16*step + 8*(lane>>5) + j, j=0..7 ->
// one dwordx4 per frag from pre-split bf16 codebook tables (prep kernel).
// -0.5*|c|^2 pre-permuted into C/D register order -> free acc init.
// No LDS / no barriers in the main loop.

constexpr int D     = 64;
constexpr int D4    = 16;     // float4s per row
constexpr int K     = 512;
constexpr int KHALF = 256;
constexpr float STH = 1e-3f;  // certainty margin in s-space (d-gap = 2*s-gap)

typedef __attribute__((ext_vector_type(8)))  short s16x8;
typedef __attribute__((ext_vector_type(16))) float f32x16;
typedef float v16f __attribute__((ext_vector_type(16)));

#define FMA4(acc, zz, cc) do { \
  acc = fmaf((zz).x, (cc).x, acc); \
  acc = fmaf((zz).y, (cc).y, acc); \
  acc = fmaf((zz).z, (cc).z, acc); \
  acc = fmaf((zz).w, (cc).w, acc); } while (0)

#define CHUNK_FMA(acc, zreg, vec, off) do { \
  acc = fmaf((zreg).x, (vec)[(off)+0], acc); \
  acc = fmaf((zreg).y, (vec)[(off)+1], acc); \
  acc = fmaf((zreg).z, (vec)[(off)+2], acc); \
  acc = fmaf((zreg).w, (vec)[(off)+3], acc); } while (0)

__device__ __forceinline__ unsigned short f2bf(float f) {
  unsigned u = __float_as_uint(f);
  return (unsigned short)((u + 0x7FFFu + ((u >> 16) & 1u)) >> 16);
}

// ---------------- prep: split codebook into bf16 hi/lo + permuted -0.5*c2 ----
__global__ void vq_prep(const float* __restrict__ cbk,
                        float* __restrict__ nhc2arr,
                        unsigned short* __restrict__ cbh,
                        unsigned short* __restrict__ cbl)
{
  int cw = blockIdx.x * blockDim.x + threadIdx.x;
  if (cw >= K) return;
  const float* c = cbk + (size_t)cw * D;
  float s = 0.f;
  for (int d = 0; d < D; ++d) {
    float f = c[d];
    s = fmaf(f, f, s);
    unsigned short hb = f2bf(f);
    float hf = __uint_as_float((unsigned)hb << 16);
    cbh[(size_t)cw * D + d] = hb;
    cbl[(size_t)cw * D + d] = f2bf(f - hf);
  }
  // invert perm(r,h) = (r&3) + 8*(r>>2) + 4*h : arranged[t*32 + h*16 + r]
  int t = cw >> 5, w = cw & 31;
  int ai = (t << 5) + (((w >> 2) & 1) << 4) + ((w >> 3) << 2) + (w & 3);
  nhc2arr[ai] = -0.5f * s;
}

// ---------------- main MFMA kernel ------------------------------------------
__global__ __launch_bounds__(256)
void vq_mfma(const float* __restrict__ z, const float* __restrict__ cbk,
             float* __restrict__ out, float* __restrict__ lossAcc,
             const unsigned short* __restrict__ cbh,
             const unsigned short* __restrict__ cbl,
             const float* __restrict__ nhc2arr,
             unsigned* __restrict__ cnt, unsigned* __restrict__ list, int N)
{
  __shared__ float wsum[4];

  const int tid  = threadIdx.x;
  const int lane = tid & 63;
  const int wave = tid >> 6;
  const int col  = lane & 31;    // this lane's z-row within the wave's 32 rows
  const int h    = lane >> 5;    // k-half / output split
  const long rowg = (long)blockIdx.x * 128 + wave * 32 + col;

  // z row -> bf16 hi/lo B-fragments. Lane holds k = 16s + 8h + j, j=0..7.
  const float4* zp4 = (const float4*)(z + (size_t)rowg * D);
  s16x8 zh[4], zl[4];
  #pragma unroll
  for (int s = 0; s < 4; ++s) {
    float4 p0 = zp4[4 * s + 2 * h];
    float4 p1 = zp4[4 * s + 2 * h + 1];
    float e[8] = {p0.x, p0.y, p0.z, p0.w, p1.x, p1.y, p1.z, p1.w};
    #pragma unroll
    for (int j = 0; j < 8; ++j) {
      unsigned short hb = f2bf(e[j]);
      float hf = __uint_as_float((unsigned)hb << 16);
      zh[s][j] = (short)hb;
      zl[s][j] = (short)f2bf(e[j] - hf);
    }
  }

  float m1 = -INFINITY, m2 = -INFINITY;
  int rbest = 0, tbest = 0;

  #pragma unroll 1
  for (int t = 0; t < 16; ++t) {
    const unsigned short* ap = cbh + (size_t)((t << 5) + col) * D + (h << 3);
    const unsigned short* lp = cbl + (size_t)((t << 5) + col) * D + (h << 3);
    s16x8 ah0 = *(const s16x8*)(ap);
    s16x8 ah1 = *(const s16x8*)(ap + 16);
    s16x8 ah2 = *(const s16x8*)(ap + 32);
    s16x8 ah3 = *(const s16x8*)(ap + 48);
    s16x8 al0 = *(const s16x8*)(lp);
    s16x8 al1 = *(const s16x8*)(lp + 16);
    s16x8 al2 = *(const s16x8*)(lp + 32);
    s16x8 al3 = *(const s16x8*)(lp + 48);

    const float4* gp = (const float4*)(nhc2arr + (t << 5) + (h << 4));
    float4 g0 = gp[0], g1 = gp[1], g2 = gp[2], g3 = gp[3];

    f32x16 acc0, acc1 = {};
    acc0[0]  = g0.x; acc0[1]  = g0.y; acc0[2]  = g0.z; acc0[3]  = g0.w;
    acc0[4]  = g1.x; acc0[5]  = g1.y; acc0[6]  = g1.z; acc0[7]  = g1.w;
    acc0[8]  = g2.x; acc0[9]  = g2.y; acc0[10] = g2.z; acc0[11] = g2.w;
    acc0[12] = g3.x; acc0[13] = g3.y; acc0[14] = g3.z; acc0[15] = g3.w;

    // hh
    acc0 = __builtin_amdgcn_mfma_f32_32x32x16_bf16(ah0, zh[0], acc0, 0, 0, 0);
    acc1 = __builtin_amdgcn_mfma_f32_32x32x16_bf16(ah1, zh[1], acc1, 0, 0, 0);
    acc0 = __builtin_amdgcn_mfma_f32_32x32x16_bf16(ah2, zh[2], acc0, 0, 0, 0);
    acc1 = __builtin_amdgcn_mfma_f32_32x32x16_bf16(ah3, zh[3], acc1, 0, 0, 0);
    // hl (codebook-hi x z-lo)
    acc0 = __builtin_amdgcn_mfma_f32_32x32x16_bf16(ah0, zl[0], acc0, 0, 0, 0);
    acc1 = __builtin_amdgcn_mfma_f32_32x32x16_bf16(ah1, zl[1], acc1, 0, 0, 0);
    acc0 = __builtin_amdgcn_mfma_f32_32x32x16_bf16(ah2, zl[2], acc0, 0, 0, 0);
    acc1 = __builtin_amdgcn_mfma_f32_32x32x16_bf16(ah3, zl[3], acc1, 0, 0, 0);
    // lh (codebook-lo x z-hi)
    acc0 = __builtin_amdgcn_mfma_f32_32x32x16_bf16(al0, zh[0], acc0, 0, 0, 0);
    acc1 = __builtin_amdgcn_mfma_f32_32x32x16_bf16(al1, zh[1], acc1, 0, 0, 0);
    acc0 = __builtin_amdgcn_mfma_f32_32x32x16_bf16(al2, zh[2], acc0, 0, 0, 0);
    acc1 = __builtin_amdgcn_mfma_f32_32x32x16_bf16(al3, zh[3], acc1, 0, 0, 0);

    const float m1pre = m1;
    #pragma unroll
    for (int r = 0; r < 16; ++r) {
      float v = acc0[r] + acc1[r];       // s = dot - 0.5*c2 (c2 in acc0 init)
      bool gt = v > m1;                  // strict: ties keep earliest (lowest cw)
      m2 = fminf(fmaxf(v, m2), m1);      // med3: new second-best (uses OLD m1)
      if (gt) rbest = r;
      m1 = gt ? v : m1;
    }
    if (m1 > m1pre) tbest = t;
  }

  // cw index from (tile, reg, half): perm(r,h) = (r&3) + 8*(r>>2) + 4h
  int idx = (tbest << 5) + (h << 2) + (rbest & 3) + ((rbest >> 2) << 3);

  // combine the two k-halves of this row (lane <-> lane^32); lower cw wins ties
  float om1  = __shfl_xor(m1, 32);
  float om2  = __shfl_xor(m2, 32);
  int   oidx = __shfl_xor(idx, 32);
  float nm2 = fmaxf(fminf(m1, om1), fmaxf(m2, om2));
  bool take = (om1 > m1) || ((om1 == m1) && (oidx < idx));
  if (take) { m1 = om1; idx = oidx; }
  m2 = nm2;

  float lacc = 0.f;
  if (m1 - m2 > STH) {
    // certain: this is provably the fp32 argmin. Epilogue identical ops to R4,
    // split across the lane pair (h picks 32-element half of the row).
    const float4* qp = (const float4*)(cbk + (size_t)idx * D) + (h << 3);
    const float4* zp = (const float4*)(z + (size_t)rowg * D) + (h << 3);
    float4*       op = (float4*)(out + (size_t)rowg * D) + (h << 3);
    #pragma unroll
    for (int i = 0; i < 8; ++i) {
      float4 q = qp[i], zz = zp[i], u, qs;
      u.x = q.x - zz.x; u.y = q.y - zz.y; u.z = q.z - zz.z; u.w = q.w - zz.w;
      qs.x = zz.x + u.x; qs.y = zz.y + u.y; qs.z = zz.z + u.z; qs.w = zz.w + u.w;
      FMA4(lacc, u, u);
      op[i] = qs;
    }
    if (h == 0) (out + (size_t)N * D + 1)[rowg] = (float)idx;
  } else if (h == 0) {
    unsigned p = atomicAdd(cnt, 1u);
    list[p] = (unsigned)rowg;
  }

  #pragma unroll
  for (int off = 32; off > 0; off >>= 1) lacc += __shfl_down(lacc, off, 64);
  if ((tid & 63) == 0) wsum[wave] = lacc;
  __syncthreads();
  if (tid == 0) atomicAdd(lossAcc, wsum[0] + wsum[1] + wsum[2] + wsum[3]);
}

// ---------------- fallback: verbatim R4 inner loop over the flagged list ----
__global__ __launch_bounds__(256)
void vq_fallback(const float* __restrict__ z, const float* __restrict__ cbk,
                 float* __restrict__ out, float* __restrict__ lossAcc,
                 const unsigned* __restrict__ list,
                 const unsigned* __restrict__ cntp, int N)
{
  __shared__ float c2s[K];
  __shared__ float mbest[128];
  __shared__ int   mbi[128];
  __shared__ float wsum[4];

  const unsigned cnt  = *cntp;
  const unsigned base = (unsigned)blockIdx.x * 128u;
  if (base >= cnt) return;

  const int tid   = threadIdx.x;
  const int local = tid & 127;
  const int khalf = tid >> 7;
  const unsigned pos = base + (unsigned)local;
  const bool active = pos < cnt;
  const long r0 = (long)list[active ? pos : (cnt - 1u)];

  for (int k = tid; k < K; k += 256) {
    const float4* c4 = (const float4*)(cbk + (size_t)k * D);
    float s = 0.f;
    #pragma unroll
    for (int i = 0; i < D4; ++i) { float4 c = c4[i]; FMA4(s, c, c); }
    c2s[k] = s;
  }

  float4 z0[D4];
  {
    const float4* zp0 = (const float4*)(z + (size_t)r0 * D);
    #pragma unroll
    for (int i = 0; i < D4; ++i) { z0[i] = zp0[i]; }
  }
  float z2_0 = 0.f;
  #pragma unroll
  for (int i = 0; i < D4; ++i) { FMA4(z2_0, z0[i], z0[i]); }

  __syncthreads();

  float best0 = INFINITY;
  int   bi0 = 0;

  const int kbeg_s = __builtin_amdgcn_readfirstlane(khalf * KHALF);
  const int kbeg   = khalf * KHALF;
  const float* cp  = cbk + (size_t)kbeg_s * D;

  #pragma unroll 1
  for (int kk = 0; kk < KHALF; ++kk) {
    const int k = kbeg + kk;
    v16f ca, cb, cc, cd;
    asm volatile("s_load_dwordx16 %0, %1, 0x0"  : "=&s"(ca) : "s"(cp));
    asm volatile("s_load_dwordx16 %0, %1, 0x40" : "=&s"(cb) : "s"(cp));
    asm volatile("s_load_dwordx16 %0, %1, 0x80" : "=&s"(cc) : "s"(cp));
    asm volatile("s_load_dwordx16 %0, %1, 0xc0" : "=&s"(cd) : "s"(cp));
    asm volatile("s_waitcnt lgkmcnt(0)"
                 : "+s"(ca), "+s"(cb), "+s"(cc), "+s"(cd));

    float a0 = 0.f, b0 = 0.f;
    CHUNK_FMA(a0, z0[0],  ca, 0);  CHUNK_FMA(b0, z0[1],  ca, 4);
    CHUNK_FMA(a0, z0[2],  ca, 8);  CHUNK_FMA(b0, z0[3],  ca, 12);
    CHUNK_FMA(a0, z0[4],  cb, 0);  CHUNK_FMA(b0, z0[5],  cb, 4);
    CHUNK_FMA(a0, z0[6],  cb, 8);  CHUNK_FMA(b0, z0[7],  cb, 12);
    CHUNK_FMA(a0, z0[8],  cc, 0);  CHUNK_FMA(b0, z0[9],  cc, 4);
    CHUNK_FMA(a0, z0[10], cc, 8);  CHUNK_FMA(b0, z0[11], cc, 12);
    CHUNK_FMA(a0, z0[12], cd, 0);  CHUNK_FMA(b0, z0[13], cd, 4);
    CHUNK_FMA(a0, z0[14], cd, 8);  CHUNK_FMA(b0, z0[15], cd, 12);

    float dot0 = a0 + b0;
    float d0 = fmaf(-2.f, dot0, z2_0) + c2s[k];
    if (d0 < best0) { best0 = d0; bi0 = k; }
    cp += D;
  }

  if (khalf == 1) { mbest[local] = best0; mbi[local] = bi0; }
  __syncthreads();

  float lacc = 0.f;
  if (khalf == 0) {
    float dhi = mbest[local];
    int   ihi = mbi[local];
    if (dhi < best0) { best0 = dhi; bi0 = ihi; }

    if (active) {
      const float4* qp = (const float4*)(cbk + (size_t)bi0 * D);
      float4* o = (float4*)(out + (size_t)r0 * D);
      #pragma unroll
      for (int i = 0; i < D4; ++i) {
        float4 q = qp[i], zz = z0[i], u, qs;
        u.x = q.x - zz.x; u.y = q.y - zz.y; u.z = q.z - zz.z; u.w = q.w - zz.w;
        qs.x = zz.x + u.x; qs.y = zz.y + u.y; qs.z = zz.z + u.z; qs.w = zz.w + u.w;
        FMA4(lacc, u, u);
        o[i] = qs;
      }
      (out + (size_t)N * D + 1)[r0] = (float)bi0;
    }
  }

  #pragma unroll
  for (int off = 32; off > 0; off >>= 1) lacc += __shfl_down(lacc, off, 64);
  if ((tid & 63) == 0) wsum[tid >> 6] = lacc;
  __syncthreads();
  if (tid == 0) {
    float s = wsum[0] + wsum[1] + wsum[2] + wsum[3];
    atomicAdd(lossAcc, s);
  }
}

__global__ void vq_finalize(float* __restrict__ out,
                            const float* __restrict__ lossAcc, int N)
{
  out[(size_t)N * D] = 1.25f * (lossAcc[0] / (float)((long)N * D));
}

extern "C" void kernel_launch(void* const* d_in, const int* in_sizes, int n_in,
                              void* d_out, int out_size, void* d_ws, size_t ws_size,
                              hipStream_t stream)
{
  const float* z   = (const float*)d_in[0];
  const float* cbk = (const float*)d_in[1];
  float* out = (float*)d_out;
  float* ws  = (float*)d_ws;
  const int N = in_sizes[0] / D;

  // ws layout (floats): [0]=lossAcc, [1]=flagCount, [64..576)=nhc2 permuted,
  // [1024..17408)=cbh (ushort), [17408..33792)=cbl (ushort), [33792..)=flag list
  float*          lossAcc = ws;
  unsigned*       cnt     = (unsigned*)(ws + 1);
  float*          nhc2arr = ws + 64;
  unsigned short* cbh     = (unsigned short*)(ws + 1024);
  unsigned short* cbl     = cbh + K * D;
  unsigned*       list    = (unsigned*)(ws + 1024 + 32768);

  hipMemsetAsync(ws, 0, 8, stream);  // clears lossAcc + flagCount
  vq_prep<<<2, 256, 0, stream>>>(cbk, nhc2arr, cbh, cbl);
  vq_mfma<<<N / 128, 256, 0, stream>>>(z, cbk, out, lossAcc, cbh, cbl,
                                       nhc2arr, cnt, list, N);
  vq_fallback<<<N / 128, 256, 0, stream>>>(z, cbk, out, lossAcc, list, cnt, N);
  vq_finalize<<<1, 1, 0, stream>>>(out, lossAcc, N);
}

// Round 3
// 371.821 us; speedup vs baseline: 1.0146x; 1.0146x over previous
//
#include <hip/hip_runtime.h>
#include <math.h>

// VQ quantizer: z [N,64] fp32, codebook [512,64] fp32.
// out layout (all fp32): q_ste [N*64] | loss [1] | ids-as-float [N]
//
// R1-R4: fp32-VALU ladder, best 374us (latency-bound on per-iter SMEM drain).
// R5: split-bf16 (hh+hl+lh) MFMA computes s = z.c - 0.5*|c|^2 (~1e-6 err);
//     rows with best-vs-runnerup margin > STH=1e-3 are provably the fp32
//     argmin; ambiguous rows go to an exact fallback. PASSED, 377us total:
//     vq_mfma 207us (MfmaUtil 10%, VALUBusy 20%, Occ 41% -> latency-bound:
//     12 VMEM loads/tile feed acc-init -> 6-deep MFMA chain -> serial scan,
//     ~3900cyc/SIMD-tile vs ~400cyc work), fallback ~55us (R4 block structure:
//     floor = one block's serial 256-iter lgkmcnt(0) latency), prep ~10us.
// R6: (a) software-pipeline codebook frag loads (manual unroll-2, double reg
//     set) so loads for t+2 issue behind tile t's body; (b) break the
//     g->acc-init->MFMA dependency: zero-init accs, add -c^2/2 in the scan
//     (FP-order change is safe: s-error stays << STH; certain/flag decisions
//     self-correct via fallback); (c) fallback rewritten wave-per-row, lanes
//     split codewords 8 each with BIT-IDENTICAL per-(row,k) chains to R4,
//     cross-lane merge = first-min; (d) vectorized prep.
// R7 = R6 resubmitted verbatim: R6's bench died with "MI355X container failed
//     twice" (broker/container infra — R1 already showed 160-218s npz pushes
//     on this link). Audit found no OOB/hang hazard in R6; keeping the source
//     bit-identical preserves a clean A/B against R5's 377us.
//
// mfma_f32_32x32x16_bf16, A=codebook(M=32 cw), B=z(N=32 rows):
//   C/D: col=lane&31 (z-row), row=(reg&3)+8*(reg>>2)+4*(lane>>5) (codeword)
//   -> per-lane 16 accs are 16 codewords of the lane's OWN row: argmin scan
//      lane-local, one shfl_xor(32) pair-combine at the end.

constexpr int D     = 64;
constexpr int D4    = 16;     // float4s per row
constexpr int K     = 512;
constexpr float STH = 1e-3f;  // certainty margin in s-space (d-gap = 2*s-gap)

typedef __attribute__((ext_vector_type(8)))  short s16x8;
typedef __attribute__((ext_vector_type(16))) float f32x16;

#define FMA4(acc, zz, cc) do { \
  acc = fmaf((zz).x, (cc).x, acc); \
  acc = fmaf((zz).y, (cc).y, acc); \
  acc = fmaf((zz).z, (cc).z, acc); \
  acc = fmaf((zz).w, (cc).w, acc); } while (0)

__device__ __forceinline__ unsigned short f2bf(float f) {
  unsigned u = __float_as_uint(f);
  return (unsigned short)((u + 0x7FFFu + ((u >> 16) & 1u)) >> 16);
}

// ---------------- prep: split codebook into bf16 hi/lo + permuted -0.5*c2 ----
__global__ void vq_prep(const float* __restrict__ cbk,
                        float* __restrict__ nhc2arr,
                        unsigned short* __restrict__ cbh,
                        unsigned short* __restrict__ cbl)
{
  int cw = blockIdx.x * 64 + threadIdx.x;
  if (cw >= K) return;
  const float4* c4 = (const float4*)(cbk + (size_t)cw * D);
  float s = 0.f;
  #pragma unroll
  for (int i = 0; i < D4; ++i) {
    float4 f = c4[i];
    FMA4(s, f, f);
    float e[4] = {f.x, f.y, f.z, f.w};
    unsigned short hh[4], ll[4];
    #pragma unroll
    for (int j = 0; j < 4; ++j) {
      unsigned short hb = f2bf(e[j]);
      float hf = __uint_as_float((unsigned)hb << 16);
      hh[j] = hb; ll[j] = f2bf(e[j] - hf);
    }
    ushort4 hv, lv;
    hv.x = hh[0]; hv.y = hh[1]; hv.z = hh[2]; hv.w = hh[3];
    lv.x = ll[0]; lv.y = ll[1]; lv.z = ll[2]; lv.w = ll[3];
    *(ushort4*)(cbh + (size_t)cw * D + i * 4) = hv;
    *(ushort4*)(cbl + (size_t)cw * D + i * 4) = lv;
  }
  // invert perm(r,h) = (r&3) + 8*(r>>2) + 4*h : arranged[t*32 + h*16 + r]
  int t = cw >> 5, w = cw & 31;
  int ai = (t << 5) + (((w >> 2) & 1) << 4) + ((w >> 3) << 2) + (w & 3);
  nhc2arr[ai] = -0.5f * s;
}

// ---------------- main MFMA kernel ------------------------------------------

#define LOAD_FRAGS(FH, FL, T) do { \
  const unsigned short* ap_ = cbh + (size_t)((((T) << 5) + col) * D) + (h << 3); \
  const unsigned short* lp_ = cbl + (size_t)((((T) << 5) + col) * D) + (h << 3); \
  FH[0] = *(const s16x8*)(ap_);      FH[1] = *(const s16x8*)(ap_ + 16); \
  FH[2] = *(const s16x8*)(ap_ + 32); FH[3] = *(const s16x8*)(ap_ + 48); \
  FL[0] = *(const s16x8*)(lp_);      FL[1] = *(const s16x8*)(lp_ + 16); \
  FL[2] = *(const s16x8*)(lp_ + 32); FL[3] = *(const s16x8*)(lp_ + 48); \
} while (0)

#define TILE_BODY(T, FH, FL) do { \
  const float4* gp_ = (const float4*)(nhc2arr + ((T) << 5) + (h << 4)); \
  float4 g0_ = gp_[0], g1_ = gp_[1], g2_ = gp_[2], g3_ = gp_[3]; \
  f32x16 acc0 = {}, acc1 = {}; \
  acc0 = __builtin_amdgcn_mfma_f32_32x32x16_bf16(FH[0], zh[0], acc0, 0, 0, 0); \
  acc1 = __builtin_amdgcn_mfma_f32_32x32x16_bf16(FH[1], zh[1], acc1, 0, 0, 0); \
  acc0 = __builtin_amdgcn_mfma_f32_32x32x16_bf16(FH[2], zh[2], acc0, 0, 0, 0); \
  acc1 = __builtin_amdgcn_mfma_f32_32x32x16_bf16(FH[3], zh[3], acc1, 0, 0, 0); \
  acc0 = __builtin_amdgcn_mfma_f32_32x32x16_bf16(FH[0], zl[0], acc0, 0, 0, 0); \
  acc1 = __builtin_amdgcn_mfma_f32_32x32x16_bf16(FH[1], zl[1], acc1, 0, 0, 0); \
  acc0 = __builtin_amdgcn_mfma_f32_32x32x16_bf16(FH[2], zl[2], acc0, 0, 0, 0); \
  acc1 = __builtin_amdgcn_mfma_f32_32x32x16_bf16(FH[3], zl[3], acc1, 0, 0, 0); \
  acc0 = __builtin_amdgcn_mfma_f32_32x32x16_bf16(FL[0], zh[0], acc0, 0, 0, 0); \
  acc1 = __builtin_amdgcn_mfma_f32_32x32x16_bf16(FL[1], zh[1], acc1, 0, 0, 0); \
  acc0 = __builtin_amdgcn_mfma_f32_32x32x16_bf16(FL[2], zh[2], acc0, 0, 0, 0); \
  acc1 = __builtin_amdgcn_mfma_f32_32x32x16_bf16(FL[3], zh[3], acc1, 0, 0, 0); \
  const float gg[16] = {g0_.x, g0_.y, g0_.z, g0_.w, g1_.x, g1_.y, g1_.z, g1_.w, \
                        g2_.x, g2_.y, g2_.z, g2_.w, g3_.x, g3_.y, g3_.z, g3_.w}; \
  const float m1pre = m1; \
  _Pragma("unroll") \
  for (int r = 0; r < 16; ++r) { \
    float v = (acc0[r] + acc1[r]) + gg[r];  /* s = dot - 0.5*c2 */ \
    bool gt = v > m1;                   /* strict: ties keep earliest */ \
    m2 = fminf(fmaxf(v, m2), m1);       /* med3: second-best (OLD m1) */ \
    if (gt) rbest = r; \
    m1 = gt ? v : m1; \
  } \
  if (m1 > m1pre) tbest = (T); \
} while (0)

__global__ __launch_bounds__(256)
void vq_mfma(const float* __restrict__ z, const float* __restrict__ cbk,
             float* __restrict__ out, float* __restrict__ lossAcc,
             const unsigned short* __restrict__ cbh,
             const unsigned short* __restrict__ cbl,
             const float* __restrict__ nhc2arr,
             unsigned* __restrict__ cnt, unsigned* __restrict__ list, int N)
{
  __shared__ float wsum[4];

  const int tid  = threadIdx.x;
  const int lane = tid & 63;
  const int wave = tid >> 6;
  const int col  = lane & 31;    // this lane's z-row within the wave's 32 rows
  const int h    = lane >> 5;    // k-half / output split
  const long rowg = (long)blockIdx.x * 128 + wave * 32 + col;

  // z row -> bf16 hi/lo B-fragments. Lane holds k = 16s + 8h + j, j=0..7.
  const float4* zp4 = (const float4*)(z + (size_t)rowg * D);
  s16x8 zh[4], zl[4];
  #pragma unroll
  for (int s = 0; s < 4; ++s) {
    float4 p0 = zp4[4 * s + 2 * h];
    float4 p1 = zp4[4 * s + 2 * h + 1];
    float e[8] = {p0.x, p0.y, p0.z, p0.w, p1.x, p1.y, p1.z, p1.w};
    #pragma unroll
    for (int j = 0; j < 8; ++j) {
      unsigned short hb = f2bf(e[j]);
      float hf = __uint_as_float((unsigned)hb << 16);
      zh[s][j] = (short)hb;
      zl[s][j] = (short)f2bf(e[j] - hf);
    }
  }

  float m1 = -INFINITY, m2 = -INFINITY;
  int rbest = 0, tbest = 0;

  // Software pipeline: two frag register sets, loads issue one body ahead so
  // the implicit waitcnt before each body's MFMAs is covered by ~1 body (~400cy).
  s16x8 FAh[4], FAl[4], FBh[4], FBl[4];
  LOAD_FRAGS(FAh, FAl, 0);
  LOAD_FRAGS(FBh, FBl, 1);
  #pragma unroll 1
  for (int t = 0; t < 14; t += 2) {
    TILE_BODY(t, FAh, FAl);
    LOAD_FRAGS(FAh, FAl, t + 2);
    TILE_BODY(t + 1, FBh, FBl);
    LOAD_FRAGS(FBh, FBl, t + 3);
  }
  TILE_BODY(14, FAh, FAl);
  TILE_BODY(15, FBh, FBl);

  // cw index from (tile, reg, half): perm(r,h) = (r&3) + 8*(r>>2) + 4h
  int idx = (tbest << 5) + (h << 2) + (rbest & 3) + ((rbest >> 2) << 3);

  // combine the two k-halves of this row (lane <-> lane^32); lower cw wins ties
  float om1  = __shfl_xor(m1, 32);
  float om2  = __shfl_xor(m2, 32);
  int   oidx = __shfl_xor(idx, 32);
  float nm2 = fmaxf(fminf(m1, om1), fmaxf(m2, om2));
  bool take = (om1 > m1) || ((om1 == m1) && (oidx < idx));
  if (take) { m1 = om1; idx = oidx; }
  m2 = nm2;

  float lacc = 0.f;
  if (m1 - m2 > STH) {
    // certain: provably the fp32 argmin. Epilogue ops identical to R4, split
    // across the lane pair (h picks the 32-element half of the row).
    const float4* qp = (const float4*)(cbk + (size_t)idx * D) + (h << 3);
    const float4* zp = (const float4*)(z + (size_t)rowg * D) + (h << 3);
    float4*       op = (float4*)(out + (size_t)rowg * D) + (h << 3);
    #pragma unroll
    for (int i = 0; i < 8; ++i) {
      float4 q = qp[i], zz = zp[i], u, qs;
      u.x = q.x - zz.x; u.y = q.y - zz.y; u.z = q.z - zz.z; u.w = q.w - zz.w;
      qs.x = zz.x + u.x; qs.y = zz.y + u.y; qs.z = zz.z + u.z; qs.w = zz.w + u.w;
      FMA4(lacc, u, u);
      op[i] = qs;
    }
    if (h == 0) (out + (size_t)N * D + 1)[rowg] = (float)idx;
  } else if (h == 0) {
    unsigned p = atomicAdd(cnt, 1u);
    list[p] = (unsigned)rowg;
  }

  #pragma unroll
  for (int off = 32; off > 0; off >>= 1) lacc += __shfl_down(lacc, off, 64);
  if ((tid & 63) == 0) wsum[tid >> 6] = lacc;
  __syncthreads();
  if (tid == 0) atomicAdd(lossAcc, wsum[0] + wsum[1] + wsum[2] + wsum[3]);
}

// ---------------- fallback: wave-per-row, exact R4 arithmetic chains --------
// Each lane handles 8 consecutive codewords (k = lane*8+j); per-(row,k) the
// FMA chains are BIT-IDENTICAL to R4 (c2: FMA4 over 16 float4s in order;
// dot: a0=even chunks / b0=odd chunks in order, dot=a0+b0;
// d = fmaf(-2,dot,z2)+c2). Cross-lane merge keeps min-d, tie -> lowest k,
// which equals numpy first-min semantics.
__global__ __launch_bounds__(256)
void vq_fallback(const float* __restrict__ z, const float* __restrict__ cbk,
                 float* __restrict__ out, float* __restrict__ lossAcc,
                 const unsigned* __restrict__ list,
                 const unsigned* __restrict__ cntp, int N)
{
  const unsigned cnt = *cntp;
  const int lane = threadIdx.x & 63;
  const unsigned wid = (blockIdx.x * blockDim.x + threadIdx.x) >> 6;
  const unsigned nw  = (gridDim.x * blockDim.x) >> 6;

  float lacc = 0.f;
  #pragma unroll 1
  for (unsigned p = wid; p < cnt; p += nw) {
    const size_t r0 = (size_t)list[p];

    const float4* zp = (const float4*)(z + r0 * D);
    float4 z0[D4];
    #pragma unroll
    for (int i = 0; i < D4; ++i) z0[i] = zp[i];
    float z2 = 0.f;
    #pragma unroll
    for (int i = 0; i < D4; ++i) FMA4(z2, z0[i], z0[i]);

    float best = INFINITY;
    int   bi = 0;
    #pragma unroll 1
    for (int j = 0; j < 8; ++j) {
      const int k = (lane << 3) + j;
      const float4* c4 = (const float4*)(cbk + (size_t)k * D);
      float4 cr[D4];
      #pragma unroll
      for (int i = 0; i < D4; ++i) cr[i] = c4[i];
      float c2 = 0.f;
      #pragma unroll
      for (int i = 0; i < D4; ++i) FMA4(c2, cr[i], cr[i]);
      float a0 = 0.f, b0 = 0.f;
      #pragma unroll
      for (int i = 0; i < 8; ++i) {
        FMA4(a0, z0[2 * i],     cr[2 * i]);
        FMA4(b0, z0[2 * i + 1], cr[2 * i + 1]);
      }
      float dot = a0 + b0;
      float d = fmaf(-2.f, dot, z2) + c2;
      if (d < best) { best = d; bi = k; }   // strict <, ascending k
    }

    #pragma unroll
    for (int off = 32; off > 0; off >>= 1) {
      float ob = __shfl_xor(best, off, 64);
      int  obi = __shfl_xor(bi, off, 64);
      if (ob < best || (ob == best && obi < bi)) { best = ob; bi = obi; }
    }

    if (lane == 0) {
      const float4* qp = (const float4*)(cbk + (size_t)bi * D);
      float4* o = (float4*)(out + r0 * D);
      #pragma unroll
      for (int i = 0; i < D4; ++i) {
        float4 q = qp[i], zz = z0[i], u, qs;
        u.x = q.x - zz.x; u.y = q.y - zz.y; u.z = q.z - zz.z; u.w = q.w - zz.w;
        qs.x = zz.x + u.x; qs.y = zz.y + u.y; qs.z = zz.z + u.z; qs.w = zz.w + u.w;
        FMA4(lacc, u, u);
        o[i] = qs;
      }
      (out + (size_t)N * D + 1)[r0] = (float)bi;
    }
  }
  if (lacc != 0.f) atomicAdd(lossAcc, lacc);
}

__global__ void vq_finalize(float* __restrict__ out,
                            const float* __restrict__ lossAcc, int N)
{
  out[(size_t)N * D] = 1.25f * (lossAcc[0] / (float)((long)N * D));
}

extern "C" void kernel_launch(void* const* d_in, const int* in_sizes, int n_in,
                              void* d_out, int out_size, void* d_ws, size_t ws_size,
                              hipStream_t stream)
{
  const float* z   = (const float*)d_in[0];
  const float* cbk = (const float*)d_in[1];
  float* out = (float*)d_out;
  float* ws  = (float*)d_ws;
  const int N = in_sizes[0] / D;

  // ws layout (floats): [0]=lossAcc, [1]=flagCount, [64..576)=nhc2 permuted,
  // [1024..17408)=cbh (ushort), [17408..33792)=cbl (ushort), [33792..)=flag list
  float*          lossAcc = ws;
  unsigned*       cnt     = (unsigned*)(ws + 1);
  float*          nhc2arr = ws + 64;
  unsigned short* cbh     = (unsigned short*)(ws + 1024);
  unsigned short* cbl     = cbh + K * D;
  unsigned*       list    = (unsigned*)(ws + 1024 + 32768);

  hipMemsetAsync(ws, 0, 8, stream);  // clears lossAcc + flagCount
  vq_prep<<<8, 64, 0, stream>>>(cbk, nhc2arr, cbh, cbl);
  vq_mfma<<<N / 128, 256, 0, stream>>>(z, cbk, out, lossAcc, cbh, cbl,
                                       nhc2arr, cnt, list, N);
  vq_fallback<<<512, 256, 0, stream>>>(z, cbk, out, lossAcc, list, cnt, N);
  vq_finalize<<<1, 1, 0, stream>>>(out, lossAcc, N);
}

// Round 4
// 214.596 us; speedup vs baseline: 1.7579x; 1.7327x over previous
//
#include <hip/hip_runtime.h>
#include <math.h>

// VQ quantizer: z [N,64] fp32, codebook [512,64] fp32.
// out layout (all fp32): q_ste [N*64] | loss [1] | ids-as-float [N]
//
// R1-R4: fp32-VALU ladder, best 374us. R5: split-bf16 (hh+hl+lh) MFMA computes
// s = z.c - 0.5*|c|^2; rows with margin > STH provably match the fp32 argmin;
// rest go to an exact fallback. 377us. R6/R7: reg double-buffer pipeline:
// vq_mfma 207->192us only — occupancy halved (41->21.6%), still latency-bound
// on 12 L2 frag loads/tile (per-tile critical path ~6.1K cyc vs ~400 issue).
// AND ~180us of the 372 total is prep+fallback: STH=1e-3 flags ~5% of rows
// (top-2 gap sigma ~0.016) and the fallback recomputed all 512 c2 chains per
// row. R8 (this):
//  (a) vq_mfma: stage both split tables (128KB) + permuted -c2/2 (2KB) in
//      133KB dynamic LDS once per block; 256 blocks (1/CU, LDS-forced), 512
//      thr, 4 row-iters each. Zero VMEM in the tile loop: frags via
//      ds_read_b128, XOR-swizzled byte^=((row&7)<<4) on BOTH fill and read
//      (row-major 128B codewords are a 32-way bank conflict unswizzled).
//      Frag+gg prefetch 1 tile ahead in a double reg set (VGPR free at 8
//      waves/CU). Scan split into two 8-chains + exact max/med merge.
//  (b) STH 1e-3 -> 2e-4: still >= 1.8x the worst-case 3-pass split error
//      bound (~1.1e-4 for the margin pair), ~5x fewer flagged rows.
//  (c) fallback: c2 from a prep table (bit-identical FMA4 chain -> same fp32
//      value), grid 1024 blocks (~1 row/wave).
//
// mfma_f32_32x32x16_bf16, A=codebook(M=32 cw), B=z(N=32 rows):
//   C/D: col=lane&31 (z-row), row=(reg&3)+8*(reg>>2)+4*(lane>>5) (codeword)
//   -> per-lane 16 accs are 16 codewords of the lane's OWN row.

constexpr int D     = 64;
constexpr int D4    = 16;      // float4s per row
constexpr int K     = 512;
constexpr float STH = 2e-4f;   // certainty margin in s-space (d-gap = 2*s-gap)

typedef __attribute__((ext_vector_type(8)))  short s16x8;
typedef __attribute__((ext_vector_type(16))) float f32x16;

#define FMA4(acc, zz, cc) do { \
  acc = fmaf((zz).x, (cc).x, acc); \
  acc = fmaf((zz).y, (cc).y, acc); \
  acc = fmaf((zz).z, (cc).z, acc); \
  acc = fmaf((zz).w, (cc).w, acc); } while (0)

__device__ __forceinline__ unsigned short f2bf(float f) {
  unsigned u = __float_as_uint(f);
  return (unsigned short)((u + 0x7FFFu + ((u >> 16) & 1u)) >> 16);
}

// ---------------- prep: split codebook into bf16 hi/lo + c2 + perm -0.5*c2 --
__global__ void vq_prep(const float* __restrict__ cbk,
                        float* __restrict__ nhc2arr,
                        float* __restrict__ c2s,
                        unsigned short* __restrict__ cbh,
                        unsigned short* __restrict__ cbl)
{
  int cw = blockIdx.x * 64 + threadIdx.x;
  if (cw >= K) return;
  const float4* c4 = (const float4*)(cbk + (size_t)cw * D);
  float s = 0.f;
  #pragma unroll
  for (int i = 0; i < D4; ++i) {
    float4 f = c4[i];
    FMA4(s, f, f);                       // same chain as the R4 fallback c2
    float e[4] = {f.x, f.y, f.z, f.w};
    unsigned short hh[4], ll[4];
    #pragma unroll
    for (int j = 0; j < 4; ++j) {
      unsigned short hb = f2bf(e[j]);
      float hf = __uint_as_float((unsigned)hb << 16);
      hh[j] = hb; ll[j] = f2bf(e[j] - hf);
    }
    ushort4 hv, lv;
    hv.x = hh[0]; hv.y = hh[1]; hv.z = hh[2]; hv.w = hh[3];
    lv.x = ll[0]; lv.y = ll[1]; lv.z = ll[2]; lv.w = ll[3];
    *(ushort4*)(cbh + (size_t)cw * D + i * 4) = hv;
    *(ushort4*)(cbl + (size_t)cw * D + i * 4) = lv;
  }
  c2s[cw] = s;                            // exact-chain c2 for the fallback
  // invert perm(r,h) = (r&3) + 8*(r>>2) + 4*h : arranged[t*32 + h*16 + r]
  int t = cw >> 5, w = cw & 31;
  int ai = (t << 5) + (((w >> 2) & 1) << 4) + ((w >> 3) << 2) + (w & 3);
  nhc2arr[ai] = -0.5f * s;
}

// ---------------- main MFMA kernel ------------------------------------------
// LDS map (dynamic, 133120 B): [0,65536) swz cbh | [65536,131072) swz cbl |
//                              [131072,133120) nhc2 (linear)

#define MFMA_B(A, B, C) __builtin_amdgcn_mfma_f32_32x32x16_bf16(A, B, C, 0, 0, 0)

#define LDS_FRAGS(CH, CL, T) do { \
  int b0_ = (((T) * 32 + col) << 7) + (h << 4); \
  CH[0] = *(const s16x8*)(smem + ((b0_      ) ^ xsw)); \
  CH[1] = *(const s16x8*)(smem + ((b0_ + 32 ) ^ xsw)); \
  CH[2] = *(const s16x8*)(smem + ((b0_ + 64 ) ^ xsw)); \
  CH[3] = *(const s16x8*)(smem + ((b0_ + 96 ) ^ xsw)); \
  CL[0] = *(const s16x8*)(smem + ((b0_ + 65536      ) ^ xsw)); \
  CL[1] = *(const s16x8*)(smem + ((b0_ + 65536 + 32 ) ^ xsw)); \
  CL[2] = *(const s16x8*)(smem + ((b0_ + 65536 + 64 ) ^ xsw)); \
  CL[3] = *(const s16x8*)(smem + ((b0_ + 65536 + 96 ) ^ xsw)); \
} while (0)

#define LDS_GG(G, T) do { \
  int gb_ = 131072 + ((((T) << 5) + (h << 4)) << 2); \
  G[0] = *(const float4*)(smem + gb_); \
  G[1] = *(const float4*)(smem + gb_ + 16); \
  G[2] = *(const float4*)(smem + gb_ + 32); \
  G[3] = *(const float4*)(smem + gb_ + 48); \
} while (0)

#define TILE_BODY(T, CH, CL, G) do { \
  f32x16 acc0 = {}, acc1 = {}; \
  acc0 = MFMA_B(CH[0], zh[0], acc0);  acc1 = MFMA_B(CH[1], zh[1], acc1); \
  acc0 = MFMA_B(CH[2], zh[2], acc0);  acc1 = MFMA_B(CH[3], zh[3], acc1); \
  acc0 = MFMA_B(CH[0], zl[0], acc0);  acc1 = MFMA_B(CH[1], zl[1], acc1); \
  acc0 = MFMA_B(CH[2], zl[2], acc0);  acc1 = MFMA_B(CH[3], zl[3], acc1); \
  acc0 = MFMA_B(CL[0], zh[0], acc0);  acc1 = MFMA_B(CL[1], zh[1], acc1); \
  acc0 = MFMA_B(CL[2], zh[2], acc0);  acc1 = MFMA_B(CL[3], zh[3], acc1); \
  const float ggv[16] = {G[0].x, G[0].y, G[0].z, G[0].w, \
                         G[1].x, G[1].y, G[1].z, G[1].w, \
                         G[2].x, G[2].y, G[2].z, G[2].w, \
                         G[3].x, G[3].y, G[3].z, G[3].w}; \
  float m1a = -INFINITY, m2a = -INFINITY, m1b = -INFINITY, m2b = -INFINITY; \
  int ra_ = 0, rb_ = 8; \
  _Pragma("unroll") \
  for (int r = 0; r < 8; ++r) { \
    float v = (acc0[r] + acc1[r]) + ggv[r]; \
    bool gt = v > m1a; \
    m2a = fminf(fmaxf(v, m2a), m1a); \
    if (gt) ra_ = r; \
    m1a = gt ? v : m1a; \
  } \
  _Pragma("unroll") \
  for (int r = 8; r < 16; ++r) { \
    float v = (acc0[r] + acc1[r]) + ggv[r]; \
    bool gt = v > m1b; \
    m2b = fminf(fmaxf(v, m2b), m1b); \
    if (gt) rb_ = r; \
    m1b = gt ? v : m1b; \
  } \
  /* perm(r,h) is monotone in r -> a-half holds the lower codewords */ \
  float tm1 = fmaxf(m1a, m1b); \
  float tm2 = fmaxf(fminf(m1a, m1b), fmaxf(m2a, m2b)); \
  int   tr_ = (m1b > m1a) ? rb_ : ra_;   /* strict: ties keep lower r */ \
  bool tgt = tm1 > m1;                   /* strict: ties keep earlier tile */ \
  m2 = fmaxf(fminf(tm1, m1), fmaxf(tm2, m2)); \
  if (tgt) { rbest = tr_; tbest = (T); } \
  m1 = tgt ? tm1 : m1; \
} while (0)

__global__ __launch_bounds__(512)
void vq_mfma(const float* __restrict__ z, const float* __restrict__ cbk,
             float* __restrict__ out, float* __restrict__ lossAcc,
             const unsigned short* __restrict__ cbh,   // cbh||cbl contiguous
             const float* __restrict__ nhc2arr,
             unsigned* __restrict__ cnt, unsigned* __restrict__ list, int N)
{
  extern __shared__ char smem[];

  const int tid  = threadIdx.x;
  const int lane = tid & 63;
  const int wave = tid >> 6;
  const int col  = lane & 31;     // this lane's z-row within the wave's 32 rows
  const int h    = lane >> 5;     // k-half / output split
  const int xsw  = (col & 7) << 4;

  // ---- fill LDS: 128KB tables (swizzled) + 2KB nhc2 (linear), once/block ---
  {
    const char* gt = (const char*)cbh;          // 131072 contiguous bytes
    #pragma unroll 4
    for (int i = tid; i < 8192; i += 512) {
      int gb = i << 4;
      int sb = gb ^ (((gb >> 7) & 7) << 4);     // row = gb>>7; chunk-XOR
      *(float4*)(smem + sb) = *(const float4*)(gt + gb);
    }
    if (tid < 128)
      *(float4*)(smem + 131072 + (tid << 4)) = ((const float4*)nhc2arr)[tid];
  }
  __syncthreads();   // tables are read-only afterwards: no more barriers

  float lacc = 0.f;

  #pragma unroll 1
  for (int it = 0; it < 4; ++it) {
    const long rowg = (long)blockIdx.x * 1024 + it * 256 + wave * 32 + col;

    // z row -> bf16 hi/lo B-frags. Lane holds k = 16s + 8h + j, j=0..7.
    const float4* zp4 = (const float4*)(z + (size_t)rowg * D);
    s16x8 zh[4], zl[4];
    #pragma unroll
    for (int s = 0; s < 4; ++s) {
      float4 p0 = zp4[4 * s + 2 * h];
      float4 p1 = zp4[4 * s + 2 * h + 1];
      float e[8] = {p0.x, p0.y, p0.z, p0.w, p1.x, p1.y, p1.z, p1.w};
      #pragma unroll
      for (int j = 0; j < 8; ++j) {
        unsigned short hb = f2bf(e[j]);
        float hf = __uint_as_float((unsigned)hb << 16);
        zh[s][j] = (short)hb;
        zl[s][j] = (short)f2bf(e[j] - hf);
      }
    }

    float m1 = -INFINITY, m2 = -INFINITY;
    int rbest = 0, tbest = 0;

    // 1-tile-ahead LDS prefetch, double reg set (VGPR free at 8 waves/CU).
    s16x8 chA[4], clA[4], chB[4], clB[4];
    float4 gA[4], gB[4];
    LDS_FRAGS(chA, clA, 0);  LDS_GG(gA, 0);
    LDS_FRAGS(chB, clB, 1);  LDS_GG(gB, 1);
    #pragma unroll 1
    for (int t = 0; t < 14; t += 2) {
      TILE_BODY(t, chA, clA, gA);
      LDS_FRAGS(chA, clA, t + 2);  LDS_GG(gA, t + 2);
      TILE_BODY(t + 1, chB, clB, gB);
      LDS_FRAGS(chB, clB, t + 3);  LDS_GG(gB, t + 3);
    }
    TILE_BODY(14, chA, clA, gA);
    TILE_BODY(15, chB, clB, gB);

    // cw index from (tile, reg, half): perm(r,h) = (r&3) + 8*(r>>2) + 4h
    int idx = (tbest << 5) + (h << 2) + (rbest & 3) + ((rbest >> 2) << 3);

    // combine the two k-halves (lane <-> lane^32); lower cw wins ties
    float om1  = __shfl_xor(m1, 32);
    float om2  = __shfl_xor(m2, 32);
    int   oidx = __shfl_xor(idx, 32);
    float nm2 = fmaxf(fminf(m1, om1), fmaxf(m2, om2));
    bool take = (om1 > m1) || ((om1 == m1) && (oidx < idx));
    if (take) { m1 = om1; idx = oidx; }
    m2 = nm2;

    if (m1 - m2 > STH) {
      // certain: provably the fp32 argmin. Epilogue ops identical to R4,
      // split across the lane pair (h picks the 32-element half of the row).
      const float4* qp = (const float4*)(cbk + (size_t)idx * D) + (h << 3);
      const float4* zp = (const float4*)(z + (size_t)rowg * D) + (h << 3);
      float4*       op = (float4*)(out + (size_t)rowg * D) + (h << 3);
      #pragma unroll
      for (int i = 0; i < 8; ++i) {
        float4 q = qp[i], zz = zp[i], u, qs;
        u.x = q.x - zz.x; u.y = q.y - zz.y; u.z = q.z - zz.z; u.w = q.w - zz.w;
        qs.x = zz.x + u.x; qs.y = zz.y + u.y; qs.z = zz.z + u.z; qs.w = zz.w + u.w;
        FMA4(lacc, u, u);
        op[i] = qs;
      }
      if (h == 0) (out + (size_t)N * D + 1)[rowg] = (float)idx;
    } else if (h == 0) {
      unsigned p = atomicAdd(cnt, 1u);
      list[p] = (unsigned)rowg;
    }
  }

  // loss: wave shuffle reduce -> one atomicAdd per wave (no LDS, no barrier)
  #pragma unroll
  for (int off = 32; off > 0; off >>= 1) lacc += __shfl_down(lacc, off, 64);
  if (lane == 0) atomicAdd(lossAcc, lacc);
}

// ---------------- fallback: wave-per-row, exact R4 arithmetic chains --------
// Lane handles 8 consecutive codewords (k = lane*8+j); per-(row,k) the FMA
// chains are BIT-IDENTICAL to R4 (c2 from prep's identical FMA4 chain; dot:
// a0=even chunks / b0=odd chunks in order; d = fmaf(-2,dot,z2)+c2).
// Cross-lane merge keeps min-d, tie -> lowest k == numpy first-min.
__global__ __launch_bounds__(256)
void vq_fallback(const float* __restrict__ z, const float* __restrict__ cbk,
                 float* __restrict__ out, float* __restrict__ lossAcc,
                 const float* __restrict__ c2s,
                 const unsigned* __restrict__ list,
                 const unsigned* __restrict__ cntp, int N)
{
  const unsigned cnt = *cntp;
  const int lane = threadIdx.x & 63;
  const unsigned wid = (blockIdx.x * blockDim.x + threadIdx.x) >> 6;
  const unsigned nw  = (gridDim.x * blockDim.x) >> 6;

  float lacc = 0.f;
  #pragma unroll 1
  for (unsigned p = wid; p < cnt; p += nw) {
    const size_t r0 = (size_t)list[p];

    const float4* zp = (const float4*)(z + r0 * D);
    float4 z0[D4];
    #pragma unroll
    for (int i = 0; i < D4; ++i) z0[i] = zp[i];
    float z2 = 0.f;
    #pragma unroll
    for (int i = 0; i < D4; ++i) FMA4(z2, z0[i], z0[i]);

    float best = INFINITY;
    int   bi = 0;
    #pragma unroll 1
    for (int j = 0; j < 8; ++j) {
      const int k = (lane << 3) + j;
      const float4* c4 = (const float4*)(cbk + (size_t)k * D);
      float4 cr[D4];
      #pragma unroll
      for (int i = 0; i < D4; ++i) cr[i] = c4[i];
      float c2 = c2s[k];                 // prep chain == R4 chain, bit-equal
      float a0 = 0.f, b0 = 0.f;
      #pragma unroll
      for (int i = 0; i < 8; ++i) {
        FMA4(a0, z0[2 * i],     cr[2 * i]);
        FMA4(b0, z0[2 * i + 1], cr[2 * i + 1]);
      }
      float dot = a0 + b0;
      float d = fmaf(-2.f, dot, z2) + c2;
      if (d < best) { best = d; bi = k; }   // strict <, ascending k
    }

    #pragma unroll
    for (int off = 32; off > 0; off >>= 1) {
      float ob = __shfl_xor(best, off, 64);
      int  obi = __shfl_xor(bi, off, 64);
      if (ob < best || (ob == best && obi < bi)) { best = ob; bi = obi; }
    }

    if (lane == 0) {
      const float4* qp = (const float4*)(cbk + (size_t)bi * D);
      float4* o = (float4*)(out + r0 * D);
      #pragma unroll
      for (int i = 0; i < D4; ++i) {
        float4 q = qp[i], zz = z0[i], u, qs;
        u.x = q.x - zz.x; u.y = q.y - zz.y; u.z = q.z - zz.z; u.w = q.w - zz.w;
        qs.x = zz.x + u.x; qs.y = zz.y + u.y; qs.z = zz.z + u.z; qs.w = zz.w + u.w;
        FMA4(lacc, u, u);
        o[i] = qs;
      }
      (out + (size_t)N * D + 1)[r0] = (float)bi;
    }
  }
  if (lacc != 0.f) atomicAdd(lossAcc, lacc);
}

__global__ void vq_finalize(float* __restrict__ out,
                            const float* __restrict__ lossAcc, int N)
{
  out[(size_t)N * D] = 1.25f * (lossAcc[0] / (float)((long)N * D));
}

extern "C" void kernel_launch(void* const* d_in, const int* in_sizes, int n_in,
                              void* d_out, int out_size, void* d_ws, size_t ws_size,
                              hipStream_t stream)
{
  const float* z   = (const float*)d_in[0];
  const float* cbk = (const float*)d_in[1];
  float* out = (float*)d_out;
  float* ws  = (float*)d_ws;
  const int N = in_sizes[0] / D;

  // ws layout (floats): [0]=lossAcc, [1]=flagCount, [64..576)=nhc2 permuted,
  // [576..1088)=c2s, [1536..34304)=cbh||cbl (ushort, 131072B contiguous),
  // [34304..)=flag list
  float*          lossAcc = ws;
  unsigned*       cnt     = (unsigned*)(ws + 1);
  float*          nhc2arr = ws + 64;
  float*          c2s     = ws + 576;
  unsigned short* cbh     = (unsigned short*)(ws + 1536);
  unsigned short* cbl     = cbh + K * D;
  unsigned*       list    = (unsigned*)(ws + 34304);

  hipMemsetAsync(ws, 0, 8, stream);  // clears lossAcc + flagCount
  vq_prep<<<8, 64, 0, stream>>>(cbk, nhc2arr, c2s, cbh, cbl);
  vq_mfma<<<N / 1024, 512, 133120, stream>>>(z, cbk, out, lossAcc, cbh,
                                             nhc2arr, cnt, list, N);
  vq_fallback<<<1024, 256, 0, stream>>>(z, cbk, out, lossAcc, c2s, list, cnt, N);
  vq_finalize<<<1, 1, 0, stream>>>(out, lossAcc, N);
}